// Round 4
// baseline (803.950 us; speedup 1.0000x reference)
//
#include <hip/hip_runtime.h>
#include <math.h>

#define NA 16
#define NBEAM 12
#define NUSER 8

// ws layout: [0 .. 1535]  : steering table, 12 beams x (16 cos | 16 sin) floats
//            [1536..1543] : double accumulator
#define ACC_OFFSET 1536

__global__ void mtl_angles_kernel(const float* __restrict__ Hc_r, const float* __restrict__ Hc_i,
                                  const float* __restrict__ Hs_r, const float* __restrict__ Hs_i,
                                  float* __restrict__ table, double* __restrict__ acc) {
    int t = threadIdx.x;
    if (t == 0) *acc = 0.0;          // zero the reduction accumulator (ws is poisoned 0xAA)
    if (t >= NBEAM) return;

    const float* re;
    const float* im;
    if (t < NUSER) { re = Hc_r + t * NA;           im = Hc_i + t * NA; }          // Hc[0, t, :]
    else           { re = Hs_r + (t - NUSER) * NA; im = Hs_i + (t - NUSER) * NA; } // Hs[0, t, :]

    const float PI_F   = 3.14159265358979323846f;
    const float TWO_PI = 6.28318530717958647692f;

    float ph[NA];
    #pragma unroll
    for (int n = 0; n < NA; ++n) ph[n] = atan2f(im[n], re[n]);

    // unwrapped[0]=0; unwrapped[n]=cumsum of wrapped diffs. n_c = n - 7.5, sum(n_c^2)=340.
    float unw = 0.f, dotsum = 0.f;
    #pragma unroll
    for (int n = 1; n < NA; ++n) {
        float pd = ph[n] - ph[n - 1];
        float x  = pd + PI_F;
        float m  = fmodf(x, TWO_PI);       // python % has sign of divisor
        if (m < 0.f) m += TWO_PI;
        pd = m - PI_F;
        unw += pd;
        dotsum += unw * ((float)n - 7.5f);
    }
    float slope = dotsum / 340.0f;
    float sin_theta = slope / PI_F;        // slope * WAVELENGTH / (2*pi*D), D=0.5, lambda=1
    sin_theta = fminf(1.0f, fmaxf(-1.0f, sin_theta));
    // angle = -asin(sin_theta); steering uses sin(angle) = -sin_theta
    float st = -sin_theta;

    #pragma unroll
    for (int n = 0; n < NA; ++n) {
        float phase = PI_F * st * (float)n;    // 2*pi*D*st*n/lambda = pi*st*n
        table[t * 2 * NA + n]      = cosf(phase);
        table[t * 2 * NA + NA + n] = sinf(phase);
    }
}

__device__ __forceinline__ float dot4(float4 a, float4 b) {
    return a.x * b.x + a.y * b.y + a.z * b.z + a.w * b.w;
}

// Async global->LDS, 16 B per lane. LDS dest is wave-uniform base + lane*16.
__device__ __forceinline__ void load_lds16(const float* g, float* l) {
    __builtin_amdgcn_global_load_lds(
        (const __attribute__((address_space(1))) void*)g,
        (__attribute__((address_space(3))) void*)l, 16, 0, 0);
}

// One beam's gain from a REGISTER-resident table row (tb[0..3]=cos, tb[4..7]=sin).
__device__ __forceinline__ float beam_gain_reg(const float4* w, const float4 (&tb)[8]) {
    float re = 0.f, im = 0.f;
    #pragma unroll
    for (int q = 0; q < 4; ++q) {
        float4 c = tb[q], s = tb[q + 4];
        float4 wr = w[q], wi = w[q + 4];
        re += dot4(wr, c) + dot4(wi, s);
        im += dot4(wi, c) - dot4(wr, s);
    }
    return sqrtf(re * re + im * im);
}

// Full-row loss (all 12 beams), table read from memory — tail path only.
__device__ __forceinline__ float row_loss(const float4* w, const float* tbl) {
    float minU = 3.4e38f, sumU = 0.f, sumT = 0.f;
    #pragma unroll 1
    for (int j = 0; j < NBEAM; ++j) {
        const float4* tc = (const float4*)(tbl + j * 32);
        float re = 0.f, im = 0.f;
        #pragma unroll
        for (int q = 0; q < 4; ++q) {
            float4 c = tc[q], s = tc[q + 4];
            float4 wr = w[q], wi = w[q + 4];
            re += dot4(wr, c) + dot4(wi, s);
            im += dot4(wi, c) - dot4(wr, s);
        }
        float g = sqrtf(re * re + im * im);
        if (j < NUSER) { minU = fminf(minU, g); sumU += g; }
        else           { sumT += g; }
    }
    return -2.0f * (minU + 0.1f * sumU) - 0.05f * sumT;
}

// R9: steering table LDS -> registers. R8 post-mortem recount: the hot loop
// issued 48 uniform-address table ds_read_b128 + 8 row ds_read_b128 per
// 32-row tile = 1.75 LDS instrs/row; at ~11 cy/ds_read_b128 that is ~58 us of
// per-CU LDS-pipe time for 2M rows on 256 CUs — exactly the measured gains
// duration. LDS read port = shared per-CU resource -> explains why TLP x2
// (R5->R7), prefetch depth x2 (R8) and beam-split (R7) were ALL null.
//  - Fix: each lane holds its 6 beams' table (48 VGPRs) in registers, loaded
//    once from global; beam/quad loops fully unrolled (static indexing only,
//    else scratch). Hot-loop LDS traffic: 8 row reads per tile = 0.25
//    instr/row, 7x less pipe (~10 us, far under HBM's 41 us).
//  - Staging unchanged from R8: triple buffer, global_load_lds w16, XOR
//    source swizzle, steady-state vmcnt(8), 48 KB LDS -> 3 blocks/CU,
//    waves_per_eu(3,3) (VGPR budget 170 >> est ~110; no R6-style squeeze).
//  - tbs LDS array + its barrier removed; tail reads table from global.
__global__ __launch_bounds__(256)
__attribute__((amdgpu_waves_per_eu(3, 3)))
void mtl_gains_kernel(const float* __restrict__ W,
                      const float* __restrict__ table,
                      double* __restrict__ acc, int rows) {
    __shared__ float sh[4 * 3 * 1024];      // 48 KB: 4 waves x 3 buffers x 4 KB
    __shared__ float wsum[4];

    const int t    = threadIdx.x;
    const int wid  = t >> 6;
    const int lane = t & 63;
    float* bA = sh + wid * 3072;
    float* bB = bA + 1024;
    float* bC = bB + 1024;

    // Pair scheme (verified R7/R8): lanes l and l^32 both process row =
    // lane&31 (same-address LDS read = broadcast). Beam partition per half
    // h = lane>>5: user beams h*4..h*4+3, target beams 8+2h, 9+2h.
    const int h   = lane >> 5;
    const int row = lane & 31;

    // Register-resident table: 4 user + 2 target beams, 8 float4 each = 48 VGPRs.
    // Uniform per half-wave -> coalesced broadcast loads from L2, once per kernel.
    float4 tU[4][8];
    float4 tT[2][8];
    {
        const float4* gt = (const float4*)table;
        #pragma unroll
        for (int b = 0; b < 4; ++b)
            #pragma unroll
            for (int q = 0; q < 8; ++q) tU[b][q] = gt[(h * 4 + b) * 8 + q];
        #pragma unroll
        for (int b = 0; b < 2; ++b)
            #pragma unroll
            for (int q = 0; q < 8; ++q) tT[b][q] = gt[(8 + h * 2 + b) * 8 + q];
    }

    // Source-side XOR swizzle (verified R5-R8): staging instr k, lane ->
    // LDS slot p = k*64+lane; row(p)=k*8+(lane>>3), q(p)=lane&7; source quad =
    // row*8 + ((lane&7) ^ (lane>>3)). LDS dest stays contiguous for
    // global_load_lds; row-major b128 reads hit all 32 banks.
    const int sq      = (lane & 7) ^ ((lane >> 3) & 7);
    const int src_off = (lane >> 3) * 32 + sq * 4;     // floats within the 1024-float tile

    const int ntiles = rows >> 5;                       // 32-row tiles (62500)
    const int nwaves = gridDim.x * 4;
    const int gw     = blockIdx.x * 4 + wid;
    const int cnt    = ntiles / nwaves;
    const int rem    = ntiles % nwaves;
    const int t0     = gw * cnt + (gw < rem ? gw : rem);
    const int t1     = t0 + cnt + (gw < rem ? 1 : 0);

    float local = 0.f;

    if (t0 < t1) {
        // prologue: stage t0 -> A, t0+1 -> B (if present). 4 loads per tile.
        {
            const float* src = W + (size_t)t0 * 1024 + src_off;
            #pragma unroll
            for (int k = 0; k < 4; ++k) load_lds16(src + k * 256, bA + k * 256);
        }
        if (t0 + 1 < t1) {
            const float* src = W + (size_t)(t0 + 1) * 1024 + src_off;
            #pragma unroll
            for (int k = 0; k < 4; ++k) load_lds16(src + k * 256, bB + k * 256);
        }
        #pragma unroll 1
        for (int tt = t0; tt < t1; ++tt) {
            if (tt + 2 < t1) {
                const float* src = W + (size_t)(tt + 2) * 1024 + src_off;
                #pragma unroll
                for (int k = 0; k < 4; ++k) load_lds16(src + k * 256, bC + k * 256);
                // outstanding: {tt, tt+1, tt+2} = 12 loads. Complete tile tt's
                // 4 (oldest); keep 2 tiles = 8 loads in flight during compute.
                asm volatile("s_waitcnt vmcnt(8)" ::: "memory");
            } else if (tt + 1 < t1) {
                asm volatile("s_waitcnt vmcnt(4)" ::: "memory");
            } else {
                asm volatile("s_waitcnt vmcnt(0)" ::: "memory");
            }

            const float* myrow = bA + row * 32;        // lanes l, l^32: same addr (broadcast)
            float4 w[8];
            #pragma unroll
            for (int q = 0; q < 8; ++q) {
                int s = q ^ (row & 7);
                w[q] = *(const float4*)(myrow + s * 4);
            }

            float minU = 3.4e38f, sumU = 0.f, sumT = 0.f;
            #pragma unroll
            for (int jj = 0; jj < 4; ++jj) {
                float g = beam_gain_reg(w, tU[jj]);
                minU = fminf(minU, g);
                sumU += g;
            }
            #pragma unroll
            for (int jj = 0; jj < 2; ++jj) {
                sumT += beam_gain_reg(w, tT[jj]);
            }
            // combine the two half-beam partials across lane pairs (l <-> l^32)
            minU = fminf(minU, __shfl_xor(minU, 32));
            sumU += __shfl_xor(sumU, 32);
            sumT += __shfl_xor(sumT, 32);
            // both lanes of the pair accumulate the full row loss -> weight 0.5
            local += 0.5f * (-2.0f * (minU + 0.1f * sumU) - 0.05f * sumT);

            // rotate buffers: A<-B (next compute), B<-C (ready), C<-A (free)
            float* tmp = bA; bA = bB; bB = bC; bC = tmp;
        }
    }

    // generic tail (rows % 32) — zero iterations for rows = 2,000,000
    int tailbase = ntiles << 5;
    if (blockIdx.x == 0) {
        int r = tailbase + t;
        if (r < rows) {
            const float4* wp = (const float4*)(W + (size_t)r * 32);
            float4 w[8];
            #pragma unroll
            for (int i = 0; i < 8; ++i) w[i] = wp[i];
            local += row_loss(w, table);   // table straight from global (cold path)
        }
    }

    // wave reduce (64 lanes)
    #pragma unroll
    for (int off = 32; off > 0; off >>= 1) local += __shfl_down(local, off);
    if (lane == 0) wsum[wid] = local;
    __syncthreads();
    if (t == 0) {
        float b = wsum[0] + wsum[1] + wsum[2] + wsum[3];
        atomicAdd(acc, (double)b);
    }
}

__global__ void mtl_finalize_kernel(const double* __restrict__ acc, float* __restrict__ out, int rows) {
    if (threadIdx.x == 0) out[0] = (float)(*acc / (double)rows);
}

extern "C" void kernel_launch(void* const* d_in, const int* in_sizes, int n_in,
                              void* d_out, int out_size, void* d_ws, size_t ws_size,
                              hipStream_t stream) {
    const float* W    = (const float*)d_in[0];
    const float* Hc_r = (const float*)d_in[1];
    const float* Hc_i = (const float*)d_in[2];
    const float* Hs_r = (const float*)d_in[3];
    const float* Hs_i = (const float*)d_in[4];
    float* out = (float*)d_out;

    int rows = in_sizes[0] / (2 * NA);   // 2,000,000
    float*  table = (float*)d_ws;
    double* acc   = (double*)((char*)d_ws + ACC_OFFSET);

    mtl_angles_kernel<<<1, 64, 0, stream>>>(Hc_r, Hc_i, Hs_r, Hs_i, table, acc);

    // 768 blocks x 4 waves = 3072 waves; 48 KB LDS/block -> 3 blocks/CU
    // resident = 12 waves/CU, prefetch depth 2, table in VGPRs.
    mtl_gains_kernel<<<768, 256, 0, stream>>>(W, table, acc, rows);

    mtl_finalize_kernel<<<1, 64, 0, stream>>>(acc, out, rows);
}

// Round 6
// 374.790 us; speedup vs baseline: 2.1451x; 2.1451x over previous
//
#include <hip/hip_runtime.h>
#include <math.h>

#define NA 16
#define NBEAM 12
#define NUSER 8

// ws layout: [0 .. 1535]  : steering table, 12 beams x (16 cos | 16 sin) floats
//            [1536..1543] : double accumulator
#define ACC_OFFSET 1536

__global__ void mtl_angles_kernel(const float* __restrict__ Hc_r, const float* __restrict__ Hc_i,
                                  const float* __restrict__ Hs_r, const float* __restrict__ Hs_i,
                                  float* __restrict__ table, double* __restrict__ acc) {
    int t = threadIdx.x;
    if (t == 0) *acc = 0.0;          // zero the reduction accumulator (ws is poisoned 0xAA)
    if (t >= NBEAM) return;

    const float* re;
    const float* im;
    if (t < NUSER) { re = Hc_r + t * NA;           im = Hc_i + t * NA; }          // Hc[0, t, :]
    else           { re = Hs_r + (t - NUSER) * NA; im = Hs_i + (t - NUSER) * NA; } // Hs[0, t, :]

    const float PI_F   = 3.14159265358979323846f;
    const float TWO_PI = 6.28318530717958647692f;

    float ph[NA];
    #pragma unroll
    for (int n = 0; n < NA; ++n) ph[n] = atan2f(im[n], re[n]);

    // unwrapped[0]=0; unwrapped[n]=cumsum of wrapped diffs. n_c = n - 7.5, sum(n_c^2)=340.
    float unw = 0.f, dotsum = 0.f;
    #pragma unroll
    for (int n = 1; n < NA; ++n) {
        float pd = ph[n] - ph[n - 1];
        float x  = pd + PI_F;
        float m  = fmodf(x, TWO_PI);       // python % has sign of divisor
        if (m < 0.f) m += TWO_PI;
        pd = m - PI_F;
        unw += pd;
        dotsum += unw * ((float)n - 7.5f);
    }
    float slope = dotsum / 340.0f;
    float sin_theta = slope / PI_F;        // slope * WAVELENGTH / (2*pi*D), D=0.5, lambda=1
    sin_theta = fminf(1.0f, fmaxf(-1.0f, sin_theta));
    // angle = -asin(sin_theta); steering uses sin(angle) = -sin_theta
    float st = -sin_theta;

    #pragma unroll
    for (int n = 0; n < NA; ++n) {
        float phase = PI_F * st * (float)n;    // 2*pi*D*st*n/lambda = pi*st*n
        table[t * 2 * NA + n]      = cosf(phase);
        table[t * 2 * NA + NA + n] = sinf(phase);
    }
}

__device__ __forceinline__ float dot4(float4 a, float4 b) {
    return a.x * b.x + a.y * b.y + a.z * b.z + a.w * b.w;
}

// Async global->LDS, 16 B per lane. LDS dest is wave-uniform base + lane*16.
__device__ __forceinline__ void load_lds16(const float* g, float* l) {
    __builtin_amdgcn_global_load_lds(
        (const __attribute__((address_space(1))) void*)g,
        (__attribute__((address_space(3))) void*)l, 16, 0, 0);
}

// One beam's gain from a register-resident table fragment (tb[0..3]=cos, tb[4..7]=sin).
__device__ __forceinline__ float beam_gain_reg(const float4* w, const float4 (&tb)[8]) {
    float re = 0.f, im = 0.f;
    #pragma unroll
    for (int q = 0; q < 4; ++q) {
        float4 c = tb[q], s = tb[q + 4];
        float4 wr = w[q], wi = w[q + 4];
        re += dot4(wr, c) + dot4(wi, s);
        im += dot4(wi, c) - dot4(wr, s);
    }
    return sqrtf(re * re + im * im);
}

// Full-row loss (all 12 beams), table from memory — tail path only.
__device__ __forceinline__ float row_loss(const float4* w, const float* tbl) {
    float minU = 3.4e38f, sumU = 0.f, sumT = 0.f;
    #pragma unroll 1
    for (int j = 0; j < NBEAM; ++j) {
        const float4* tc = (const float4*)(tbl + j * 32);
        float re = 0.f, im = 0.f;
        #pragma unroll
        for (int q = 0; q < 4; ++q) {
            float4 c = tc[q], s = tc[q + 4];
            float4 wr = w[q], wi = w[q + 4];
            re += dot4(wr, c) + dot4(wi, s);
            im += dot4(wi, c) - dot4(wr, s);
        }
        float g = sqrtf(re * re + im * im);
        if (j < NUSER) { minU = fminf(minU, g); sumU += g; }
        else           { sumT += g; }
    }
    return -2.0f * (minU + 0.1f * sumU) - 0.05f * sumT;
}

// R10 (resubmit; R5 bench was an infra failure — container acquisition died,
// kernel never ran). Model (R8/R9 post-mortems): gains is LDS-read-pipe bound
// — table reads are uniform b128s issued per tile-pass; R7/R8 = 1.75
// ds_read/row x ~11cy = ~58us on 256 CUs = measured. R9 (table in VGPRs)
// spilled: 6 beams x 8 float4 = 192 VGPRs, scratch traffic 1.7GB fetch /
// 220MB write. This round keeps the table in LDS but:
//  - 64-row tiles + pair-split: lanes l,l^32 process rows (lane&31) and
//    (lane&31)+32, 6 beams each; each beam's 8-quad fragment is read from LDS
//    ONCE per tile, reused for both rows (#pragma unroll 1 keeps exactly one
//    32-VGPR fragment live -> no R9 spill; est. ~130 VGPR, budget 256 via
//    waves_per_eu(2,2)).
//  - Per 64-row tile: 16 row + 48 table = 64 ds_read_b128 = 1.0/row (vs 1.75)
//    -> LDS pipe ~34us, below the memory floor (~38-41us; R8 FETCH showed
//    half of W streams from L3).
//  - Staging = R5's verified 64-row double-buffer: 8 x global_load_lds w16,
//    XOR source swizzle (rows r, r+32 share r&7 -> same read phase), in-loop
//    vmcnt(8), depth 1 (R8 proved depth 2 null). 64KB + table -> 2 blocks/CU
//    = 8 waves/CU (R5<->R7 proved 8 vs 16 waves neutral).
__global__ __launch_bounds__(256)
__attribute__((amdgpu_waves_per_eu(2, 2)))
void mtl_gains_kernel(const float* __restrict__ W,
                      const float* __restrict__ table,
                      double* __restrict__ acc, int rows) {
    __shared__ float sh[4 * 2 * 2048];      // 64 KB: 4 waves x 2 buffers x 8 KB
    __shared__ float tbs[NBEAM * 2 * NA];   // steering table, 384 floats
    __shared__ float wsum[4];

    const int t = threadIdx.x;
    for (int i = t; i < NBEAM * 2 * NA; i += blockDim.x) tbs[i] = table[i];
    __syncthreads();

    const int wid  = t >> 6;
    const int lane = t & 63;
    float* buf0 = sh + wid * 4096;
    float* buf1 = buf0 + 2048;

    // Pair scheme (verified R7/R8): lanes l and l^32 read the same addresses
    // (broadcast). Beam partition per half h = lane>>5: user beams h*4..h*4+3,
    // target beams 8+2h, 9+2h; combine via 3 shfl_xor(32) per row.
    const int h      = lane >> 5;
    const int row    = lane & 31;
    const float* tbU = tbs + h * 4 * 32;
    const float* tbT = tbs + (8 + h * 2) * 32;

    // Source-side XOR swizzle (verified R5): staging instr k (0..7), lane ->
    // LDS slot p = k*64+lane (quads); row(p)=k*8+(lane>>3), q(p)=lane&7;
    // source quad = row*8 + ((lane&7) ^ ((lane>>3)&7)). LDS dest stays
    // contiguous for global_load_lds; row-major b128 reads spread banks.
    const int sq      = (lane & 7) ^ ((lane >> 3) & 7);
    const int src_off = (lane >> 3) * 32 + sq * 4;     // floats within the 2048-float tile

    const int ntiles = rows >> 6;                       // 64-row tiles (31250)
    const int nwaves = gridDim.x * 4;
    const int gw     = blockIdx.x * 4 + wid;
    const int cnt    = ntiles / nwaves;
    const int rem    = ntiles % nwaves;
    const int t0     = gw * cnt + (gw < rem ? gw : rem);
    const int t1     = t0 + cnt + (gw < rem ? 1 : 0);

    float local = 0.f;

    if (t0 < t1) {
        // prologue: stage tile t0 into buf0 (8 x 1 KB)
        {
            const float* src = W + (size_t)t0 * 2048 + src_off;
            #pragma unroll
            for (int k = 0; k < 8; ++k) load_lds16(src + k * 256, buf0 + k * 256);
        }
        #pragma unroll 1
        for (int tt = t0; tt < t1; ++tt) {
            float* cur = ((tt - t0) & 1) ? buf1 : buf0;
            float* nxt = ((tt - t0) & 1) ? buf0 : buf1;
            if (tt + 1 < t1) {
                const float* src = W + (size_t)(tt + 1) * 2048 + src_off;
                #pragma unroll
                for (int k = 0; k < 8; ++k) load_lds16(src + k * 256, nxt + k * 256);
                // 16 staging loads outstanding; wait for tile tt's 8 (oldest),
                // keep tile tt+1's 8 in flight through the compute below.
                asm volatile("s_waitcnt vmcnt(8)" ::: "memory");
            } else {
                asm volatile("s_waitcnt vmcnt(0)" ::: "memory");
            }

            // two rows per lane-pair: row (lane&31) and row+32. Same swizzle
            // phase for both (32 = 0 mod 8). Lanes l, l^32: same addr = broadcast.
            const float* r0 = cur + row * 32;
            const float* r1 = cur + (row + 32) * 32;
            float4 w0[8], w1[8];
            #pragma unroll
            for (int q = 0; q < 8; ++q) {
                int s = q ^ (row & 7);
                w0[q] = *(const float4*)(r0 + s * 4);
                w1[q] = *(const float4*)(r1 + s * 4);
            }

            float minU0 = 3.4e38f, sumU0 = 0.f, sumT0 = 0.f;
            float minU1 = 3.4e38f, sumU1 = 0.f, sumT1 = 0.f;
            #pragma unroll 1
            for (int jj = 0; jj < 4; ++jj) {
                const float4* tc = (const float4*)(tbU + jj * 32);
                float4 tb[8];
                #pragma unroll
                for (int q = 0; q < 8; ++q) tb[q] = tc[q];   // 8 uniform b128, reused 2x
                float g0 = beam_gain_reg(w0, tb);
                float g1 = beam_gain_reg(w1, tb);
                minU0 = fminf(minU0, g0); sumU0 += g0;
                minU1 = fminf(minU1, g1); sumU1 += g1;
            }
            #pragma unroll 1
            for (int jj = 0; jj < 2; ++jj) {
                const float4* tc = (const float4*)(tbT + jj * 32);
                float4 tb[8];
                #pragma unroll
                for (int q = 0; q < 8; ++q) tb[q] = tc[q];
                sumT0 += beam_gain_reg(w0, tb);
                sumT1 += beam_gain_reg(w1, tb);
            }
            // combine the half-beam partials across lane pairs (l <-> l^32)
            minU0 = fminf(minU0, __shfl_xor(minU0, 32));
            sumU0 += __shfl_xor(sumU0, 32);
            sumT0 += __shfl_xor(sumT0, 32);
            minU1 = fminf(minU1, __shfl_xor(minU1, 32));
            sumU1 += __shfl_xor(sumU1, 32);
            sumT1 += __shfl_xor(sumT1, 32);
            // both lanes of the pair accumulate each row's full loss -> weight 0.5
            local += 0.5f * (-2.0f * (minU0 + 0.1f * sumU0) - 0.05f * sumT0);
            local += 0.5f * (-2.0f * (minU1 + 0.1f * sumU1) - 0.05f * sumT1);
        }
    }

    // generic tail (rows % 64) — zero iterations for rows = 2,000,000
    int tailbase = ntiles << 6;
    if (blockIdx.x == 0) {
        int r = tailbase + t;
        if (r < rows) {
            const float4* wp = (const float4*)(W + (size_t)r * 32);
            float4 w[8];
            #pragma unroll
            for (int i = 0; i < 8; ++i) w[i] = wp[i];
            local += row_loss(w, table);   // table straight from global (cold path)
        }
    }

    // wave reduce (64 lanes)
    #pragma unroll
    for (int off = 32; off > 0; off >>= 1) local += __shfl_down(local, off);
    if (lane == 0) wsum[wid] = local;
    __syncthreads();
    if (t == 0) {
        float b = wsum[0] + wsum[1] + wsum[2] + wsum[3];
        atomicAdd(acc, (double)b);
    }
}

__global__ void mtl_finalize_kernel(const double* __restrict__ acc, float* __restrict__ out, int rows) {
    if (threadIdx.x == 0) out[0] = (float)(*acc / (double)rows);
}

extern "C" void kernel_launch(void* const* d_in, const int* in_sizes, int n_in,
                              void* d_out, int out_size, void* d_ws, size_t ws_size,
                              hipStream_t stream) {
    const float* W    = (const float*)d_in[0];
    const float* Hc_r = (const float*)d_in[1];
    const float* Hc_i = (const float*)d_in[2];
    const float* Hs_r = (const float*)d_in[3];
    const float* Hs_i = (const float*)d_in[4];
    float* out = (float*)d_out;

    int rows = in_sizes[0] / (2 * NA);   // 2,000,000
    float*  table = (float*)d_ws;
    double* acc   = (double*)((char*)d_ws + ACC_OFFSET);

    mtl_angles_kernel<<<1, 64, 0, stream>>>(Hc_r, Hc_i, Hs_r, Hs_i, table, acc);

    // 512 blocks x 4 waves = 2048 waves; ~66 KB LDS/block -> 2 blocks/CU
    // resident = 8 waves/CU; 1.0 ds_read_b128 per row (was 1.75).
    mtl_gains_kernel<<<512, 256, 0, stream>>>(W, table, acc, rows);

    mtl_finalize_kernel<<<1, 64, 0, stream>>>(acc, out, rows);
}